// Round 4
// baseline (815.093 us; speedup 1.0000x reference)
//
#include <hip/hip_runtime.h>
#include <hip/hip_cooperative_groups.h>
#include <math.h>

namespace cg = cooperative_groups;

// LGTCN layer on MI355X — round 4: single cooperative mega-kernel.
// Phases (grid.sync between): prep (S->bf16 tiled, z/W transpose) ->
// diffuseA (S@[u|x0], split-K fp32 partials) -> update1 (fused reduce +
// tap-MFMA + ODE + xtT pack) -> 3x [diffuseS -> update_step].
// Layouts (proven in round 3):
//   SbT[tap][kb][n][kw32] bf16, ztT[kb][d][kw32] bf16,
//   WtT[(mat*6+s)*64+e][kw32] bf16, Yp slices [n][64] fp32.
// n_steps fixed at 4 by setup_inputs().

typedef unsigned short u16;
typedef unsigned int u32;
typedef __attribute__((ext_vector_type(8))) short short8;
typedef __attribute__((ext_vector_type(4))) float f32x4;

#define NN 4096
#define HD 64
#define DT_C 0.05f

__device__ __forceinline__ u16 f2bf(float f) {
    u32 u = __float_as_uint(f);
    u += 0x7FFFu + ((u >> 16) & 1u);   // RNE
    return (u16)(u >> 16);
}
__device__ __forceinline__ u32 pk2(float a, float b) {
    return (u32)f2bf(a) | ((u32)f2bf(b) << 16);
}
__device__ __forceinline__ short8 pkfrag(const float4& a, const float4& b) {
    union { short8 s; u32 w[4]; } r;
    r.w[0] = pk2(a.x, a.y); r.w[1] = pk2(a.z, a.w);
    r.w[2] = pk2(b.x, b.y); r.w[3] = pk2(b.z, b.w);
    return r.s;
}
__device__ __forceinline__ void add4(float4& d, const float4& v) {
    d.x += v.x; d.y += v.y; d.z += v.z; d.w += v.w;
}
#define MFMA __builtin_amdgcn_mfma_f32_16x16x32_bf16

// ---------------- phase 0: prep ----------------
__device__ void prep_phase(const float* S, const float* u, const float* x0,
                           const float* WAh, const float* WAs,
                           const float* WBh, const float* WBs,
                           u16* SbT, u16* utT, u16* xtT, u16* WtT)
{
    const int t = threadIdx.x;
    __shared__ __align__(16) u16 tile[64][40];
    for (int uu = blockIdx.x; uu < 24576 + 257; uu += 256) {
        if (uu < 24576) {
            // convS unit: 64 rows x one 32-wide k-slab
            const int nx = uu & 63, slab = uu >> 6;          // slab = tap*128+kb
            const int tap = slab >> 7, kb = slab & 127;
            const int n = nx * 64 + (t >> 2), kq = (t & 3) * 8;
            const float* src = S + ((size_t)tap * NN + n) * NN + kb * 32 + kq;
            float4 f0 = ((const float4*)src)[0];
            float4 f1 = ((const float4*)src)[1];
            uint4 o;
            o.x = pk2(f0.x, f0.y); o.y = pk2(f0.z, f0.w);
            o.z = pk2(f1.x, f1.y); o.w = pk2(f1.z, f1.w);
            *(uint4*)(SbT + ((size_t)slab * NN + n) * 32 + kq) = o;
        } else if (uu < 24832) {
            // zprep unit: one kb-slab (32 rows) of u or x0 -> tiled bf16
            const int zu = uu - 24576;
            const float* z = (zu < 128) ? u : x0;
            u16* ztT = (zu < 128) ? utT : xtT;
            const int kb = zu & 127, n0 = kb * 32;
            const int nl = t >> 3, c0 = (t & 7) * 8;
            const float* srcz = z + (size_t)(n0 + nl) * HD + c0;
            float4 f0 = ((const float4*)srcz)[0];
            float4 f1 = ((const float4*)srcz)[1];
            tile[c0 + 0][nl] = f2bf(f0.x); tile[c0 + 1][nl] = f2bf(f0.y);
            tile[c0 + 2][nl] = f2bf(f0.z); tile[c0 + 3][nl] = f2bf(f0.w);
            tile[c0 + 4][nl] = f2bf(f1.x); tile[c0 + 5][nl] = f2bf(f1.y);
            tile[c0 + 6][nl] = f2bf(f1.z); tile[c0 + 7][nl] = f2bf(f1.w);
            __syncthreads();
            const int e = t >> 2, kw0 = (t & 3) * 8;
            short8 v = *(const short8*)&tile[e][kw0];
            *(short8*)(ztT + ((size_t)kb * 64 + e) * 32 + kw0) = v;
            __syncthreads();   // tile reused next loop iter
        } else {
            // WtT[((mat*6+s)*64+e)*32+kw] = W[mat][kp>>6][kp&63][e], kp=s*32+kw
            for (int f = t; f < 4 * 6 * 64 * 32; f += 256) {
                int mat = f / 12288, r = f % 12288;
                int s = r / 2048, r2 = r % 2048;
                int e = r2 >> 5, kw = r2 & 31;
                int kp = s * 32 + kw, tap = kp >> 6, d = kp & 63;
                const float* Wm = (mat == 0) ? WAh : (mat == 1) ? WAs
                                 : (mat == 2) ? WBh : WBs;
                WtT[f] = f2bf(Wm[((size_t)tap * HD + d) * HD + e]);
            }
        }
    }
}

// ---------------- diffuse step: Yp[ks*3+tap] = S[tap] @ x (partial-K) ----------------
__device__ void diffuse_step_phase(const u16* SbT, const u16* xtT,
                                   float* Yp, int KS)
{
    const int t = threadIdx.x;
    const int w = t >> 6, lane = t & 63, l15 = lane & 15, quad = lane >> 4;
    const int iters = 128 / KS;
    for (int uu = blockIdx.x; uu < 96 * KS; uu += 256) {
        const int rowblk = uu & 31;
        const int tmp = uu >> 5;
        const int ks = tmp % KS, tap = tmp / KS;
        const int row0 = rowblk * 128;
        const int slab0 = tap * 128 + ks * iters;
        const int kb0 = ks * iters;
        const u16* A0 = SbT + ((size_t)slab0 * NN + row0 + w * 32 + l15) * 32 + quad * 8;
        const u16* B0 = xtT + ((size_t)kb0 * 64 + l15) * 32 + quad * 8;

        f32x4 z4 = {0.f, 0.f, 0.f, 0.f};
        f32x4 acc[2][4];
        #pragma unroll
        for (int i = 0; i < 2; ++i)
            #pragma unroll
            for (int j = 0; j < 4; ++j) acc[i][j] = z4;

        short8 a0 = *(const short8*)(A0);
        short8 a1 = *(const short8*)(A0 + 512);
        short8 b0 = *(const short8*)(B0);
        short8 b1 = *(const short8*)(B0 + 512);
        short8 b2 = *(const short8*)(B0 + 1024);
        short8 b3 = *(const short8*)(B0 + 1536);
        for (int kb = 1; kb < iters; ++kb) {
            const u16* An = A0 + (size_t)kb * (NN * 32);
            const u16* Bn = B0 + (size_t)kb * 2048;
            short8 na0 = *(const short8*)(An);
            short8 na1 = *(const short8*)(An + 512);
            short8 nb0 = *(const short8*)(Bn);
            short8 nb1 = *(const short8*)(Bn + 512);
            short8 nb2 = *(const short8*)(Bn + 1024);
            short8 nb3 = *(const short8*)(Bn + 1536);
            acc[0][0] = MFMA(a0, b0, acc[0][0], 0, 0, 0);
            acc[1][0] = MFMA(a1, b0, acc[1][0], 0, 0, 0);
            acc[0][1] = MFMA(a0, b1, acc[0][1], 0, 0, 0);
            acc[1][1] = MFMA(a1, b1, acc[1][1], 0, 0, 0);
            acc[0][2] = MFMA(a0, b2, acc[0][2], 0, 0, 0);
            acc[1][2] = MFMA(a1, b2, acc[1][2], 0, 0, 0);
            acc[0][3] = MFMA(a0, b3, acc[0][3], 0, 0, 0);
            acc[1][3] = MFMA(a1, b3, acc[1][3], 0, 0, 0);
            a0 = na0; a1 = na1; b0 = nb0; b1 = nb1; b2 = nb2; b3 = nb3;
        }
        acc[0][0] = MFMA(a0, b0, acc[0][0], 0, 0, 0);
        acc[1][0] = MFMA(a1, b0, acc[1][0], 0, 0, 0);
        acc[0][1] = MFMA(a0, b1, acc[0][1], 0, 0, 0);
        acc[1][1] = MFMA(a1, b1, acc[1][1], 0, 0, 0);
        acc[0][2] = MFMA(a0, b2, acc[0][2], 0, 0, 0);
        acc[1][2] = MFMA(a1, b2, acc[1][2], 0, 0, 0);
        acc[0][3] = MFMA(a0, b3, acc[0][3], 0, 0, 0);
        acc[1][3] = MFMA(a1, b3, acc[1][3], 0, 0, 0);

        float* yb = Yp + ((size_t)(ks * 3 + tap) * NN + row0) * HD;
        #pragma unroll
        for (int rt = 0; rt < 2; ++rt)
            #pragma unroll
            for (int ct = 0; ct < 4; ++ct)
                #pragma unroll
                for (int r = 0; r < 4; ++r)
                    yb[(size_t)(w * 32 + rt * 16 + quad * 4 + r) * HD + ct * 16 + l15] =
                        acc[rt][ct][r];
    }
}

// ---------------- diffuse A: Yp[(ks*3+tap)*2+src] = S[tap] @ {u,x0} ----------------
__device__ void diffuseA_phase(const u16* SbT, const u16* utT, const u16* xtT,
                               float* Yp, int KS)
{
    const int t = threadIdx.x;
    const int w = t >> 6, lane = t & 63, l15 = lane & 15, quad = lane >> 4;
    const int iters = 128 / KS;
    for (int uu = blockIdx.x; uu < 96 * KS; uu += 256) {
        const int rowblk = uu & 31;
        const int tmp = uu >> 5;
        const int ks = tmp % KS, tap = tmp / KS;
        const int row0 = rowblk * 128;
        const int slab0 = tap * 128 + ks * iters;
        const int kb0 = ks * iters;
        const u16* A0 = SbT + ((size_t)slab0 * NN + row0 + w * 32 + l15) * 32 + quad * 8;
        const size_t boff = ((size_t)kb0 * 64 + l15) * 32 + quad * 8;

        f32x4 z4 = {0.f, 0.f, 0.f, 0.f};
        f32x4 acc[2][2][4];   // [src][rt][ct]
        #pragma unroll
        for (int s = 0; s < 2; ++s)
            #pragma unroll
            for (int i = 0; i < 2; ++i)
                #pragma unroll
                for (int j = 0; j < 4; ++j) acc[s][i][j] = z4;

        short8 a0 = *(const short8*)(A0);
        short8 a1 = *(const short8*)(A0 + 512);
        short8 bu0 = *(const short8*)(utT + boff);
        short8 bu1 = *(const short8*)(utT + boff + 512);
        short8 bu2 = *(const short8*)(utT + boff + 1024);
        short8 bu3 = *(const short8*)(utT + boff + 1536);
        short8 bx0 = *(const short8*)(xtT + boff);
        short8 bx1 = *(const short8*)(xtT + boff + 512);
        short8 bx2 = *(const short8*)(xtT + boff + 1024);
        short8 bx3 = *(const short8*)(xtT + boff + 1536);
        for (int kb = 1; kb < iters; ++kb) {
            const u16* An = A0 + (size_t)kb * (NN * 32);
            const size_t bn = boff + (size_t)kb * 2048;
            short8 na0 = *(const short8*)(An);
            short8 na1 = *(const short8*)(An + 512);
            short8 nu0 = *(const short8*)(utT + bn);
            short8 nu1 = *(const short8*)(utT + bn + 512);
            short8 nu2 = *(const short8*)(utT + bn + 1024);
            short8 nu3 = *(const short8*)(utT + bn + 1536);
            short8 nx0 = *(const short8*)(xtT + bn);
            short8 nx1 = *(const short8*)(xtT + bn + 512);
            short8 nx2 = *(const short8*)(xtT + bn + 1024);
            short8 nx3 = *(const short8*)(xtT + bn + 1536);
            acc[0][0][0] = MFMA(a0, bu0, acc[0][0][0], 0, 0, 0);
            acc[0][1][0] = MFMA(a1, bu0, acc[0][1][0], 0, 0, 0);
            acc[0][0][1] = MFMA(a0, bu1, acc[0][0][1], 0, 0, 0);
            acc[0][1][1] = MFMA(a1, bu1, acc[0][1][1], 0, 0, 0);
            acc[0][0][2] = MFMA(a0, bu2, acc[0][0][2], 0, 0, 0);
            acc[0][1][2] = MFMA(a1, bu2, acc[0][1][2], 0, 0, 0);
            acc[0][0][3] = MFMA(a0, bu3, acc[0][0][3], 0, 0, 0);
            acc[0][1][3] = MFMA(a1, bu3, acc[0][1][3], 0, 0, 0);
            acc[1][0][0] = MFMA(a0, bx0, acc[1][0][0], 0, 0, 0);
            acc[1][1][0] = MFMA(a1, bx0, acc[1][1][0], 0, 0, 0);
            acc[1][0][1] = MFMA(a0, bx1, acc[1][0][1], 0, 0, 0);
            acc[1][1][1] = MFMA(a1, bx1, acc[1][1][1], 0, 0, 0);
            acc[1][0][2] = MFMA(a0, bx2, acc[1][0][2], 0, 0, 0);
            acc[1][1][2] = MFMA(a1, bx2, acc[1][1][2], 0, 0, 0);
            acc[1][0][3] = MFMA(a0, bx3, acc[1][0][3], 0, 0, 0);
            acc[1][1][3] = MFMA(a1, bx3, acc[1][1][3], 0, 0, 0);
            a0 = na0; a1 = na1;
            bu0 = nu0; bu1 = nu1; bu2 = nu2; bu3 = nu3;
            bx0 = nx0; bx1 = nx1; bx2 = nx2; bx3 = nx3;
        }
        acc[0][0][0] = MFMA(a0, bu0, acc[0][0][0], 0, 0, 0);
        acc[0][1][0] = MFMA(a1, bu0, acc[0][1][0], 0, 0, 0);
        acc[0][0][1] = MFMA(a0, bu1, acc[0][0][1], 0, 0, 0);
        acc[0][1][1] = MFMA(a1, bu1, acc[0][1][1], 0, 0, 0);
        acc[0][0][2] = MFMA(a0, bu2, acc[0][0][2], 0, 0, 0);
        acc[0][1][2] = MFMA(a1, bu2, acc[0][1][2], 0, 0, 0);
        acc[0][0][3] = MFMA(a0, bu3, acc[0][0][3], 0, 0, 0);
        acc[0][1][3] = MFMA(a1, bu3, acc[0][1][3], 0, 0, 0);
        acc[1][0][0] = MFMA(a0, bx0, acc[1][0][0], 0, 0, 0);
        acc[1][1][0] = MFMA(a1, bx0, acc[1][1][0], 0, 0, 0);
        acc[1][0][1] = MFMA(a0, bx1, acc[1][0][1], 0, 0, 0);
        acc[1][1][1] = MFMA(a1, bx1, acc[1][1][1], 0, 0, 0);
        acc[1][0][2] = MFMA(a0, bx2, acc[1][0][2], 0, 0, 0);
        acc[1][1][2] = MFMA(a1, bx2, acc[1][1][2], 0, 0, 0);
        acc[1][0][3] = MFMA(a0, bx3, acc[1][0][3], 0, 0, 0);
        acc[1][1][3] = MFMA(a1, bx3, acc[1][1][3], 0, 0, 0);

        #pragma unroll
        for (int s = 0; s < 2; ++s) {
            float* yb = Yp + ((size_t)((ks * 3 + tap) * 2 + s) * NN + row0) * HD;
            #pragma unroll
            for (int rt = 0; rt < 2; ++rt)
                #pragma unroll
                for (int ct = 0; ct < 4; ++ct)
                    #pragma unroll
                    for (int r = 0; r < 4; ++r)
                        yb[(size_t)(w * 32 + rt * 16 + quad * 4 + r) * HD + ct * 16 + l15] =
                            acc[s][rt][ct][r];
        }
    }
}

// ---------------- update step: fused reduce + tap MFMA + ODE + pack ----------------
// 256 blocks x 4 waves; wave w handles output cols [w*16, w*16+16).
__device__ void update_step_phase(const float* Yp, int KS, const u16* WtT,
                                  const float* bx, const float* bvec,
                                  const float* fu, const float* sc,
                                  const float* xc, float* xn, u16* xtT)
{
    const int t = threadIdx.x;
    const int w = t >> 6, lane = t & 63, l15 = lane & 15, quad = lane >> 4;
    const int n0 = blockIdx.x * 16;
    f32x4 aF = {0.f, 0.f, 0.f, 0.f}, aG = aF;
    #pragma unroll
    for (int s = 0; s < 6; ++s) {
        const float* base = Yp + ((size_t)(s >> 1) * NN + n0 + l15) * HD
                               + (s & 1) * 32 + quad * 8;
        float4 p0 = {0.f, 0.f, 0.f, 0.f}, p1 = p0;
        for (int ks = 0; ks < KS; ++ks) {
            const float* pp = base + (size_t)ks * 3 * NN * HD;
            add4(p0, ((const float4*)pp)[0]);
            add4(p1, ((const float4*)pp)[1]);
        }
        short8 a = pkfrag(p0, p1);
        const size_t wo = ((size_t)s * 64 + w * 16 + l15) * 32 + quad * 8;
        short8 bF = *(const short8*)(WtT + wo);            // WA_hat
        short8 bG = *(const short8*)(WtT + wo + 12288);    // WA_state
        aF = MFMA(a, bF, aF, 0, 0, 0);
        aG = MFMA(a, bG, aG, 0, 0, 0);
    }
    const int e = w * 16 + l15;
    const float bxv = bx[e], bbv = bvec[e];
    #pragma unroll
    for (int r = 0; r < 4; ++r) {
        const int n = n0 + quad * 4 + r;
        const size_t o = (size_t)n * HD + e;
        float f = fmaxf(aF[r] + bxv, 0.f) + fu[o];
        float xv = xc[o];
        float dx = -(bbv + f) * xv - aG[r] + f * sc[o];
        float xnv = fminf(fmaxf(xv + DT_C * dx, -1.f), 1.f);
        xn[o] = xnv;
        xtT[((size_t)(n >> 5) * 64 + e) * 32 + (n & 31)] = f2bf(xnv);
    }
}

__device__ void update1_phase(const float* Yp, int KS, const u16* WtT,
                              const float* bx, const float* bu, const float* bvec,
                              const float* x0, float* fu, float* sc,
                              float* xn, u16* xtT)
{
    const int t = threadIdx.x;
    const int w = t >> 6, lane = t & 63, l15 = lane & 15, quad = lane >> 4;
    const int n0 = blockIdx.x * 16;
    f32x4 aF = {0.f, 0.f, 0.f, 0.f}, aG = aF, aFu = aF, aSc = aF;
    #pragma unroll
    for (int s = 0; s < 6; ++s) {
        const float* baseu = Yp + ((size_t)((s >> 1) * 2 + 0) * NN + n0 + l15) * HD
                                + (s & 1) * 32 + quad * 8;
        const float* basex = baseu + (size_t)NN * HD;
        float4 pu0 = {0.f, 0.f, 0.f, 0.f}, pu1 = pu0, px0 = pu0, px1 = pu0;
        for (int ks = 0; ks < KS; ++ks) {
            const float* ppu = baseu + (size_t)ks * 6 * NN * HD;
            const float* ppx = basex + (size_t)ks * 6 * NN * HD;
            add4(pu0, ((const float4*)ppu)[0]);
            add4(pu1, ((const float4*)ppu)[1]);
            add4(px0, ((const float4*)ppx)[0]);
            add4(px1, ((const float4*)ppx)[1]);
        }
        short8 au = pkfrag(pu0, pu1);
        short8 ax = pkfrag(px0, px1);
        const size_t wo = ((size_t)s * 64 + w * 16 + l15) * 32 + quad * 8;
        short8 bF  = *(const short8*)(WtT + wo);            // WA_hat
        short8 bG  = *(const short8*)(WtT + wo + 12288);    // WA_state
        short8 bFu = *(const short8*)(WtT + wo + 24576);    // WB_hat
        short8 bSc = *(const short8*)(WtT + wo + 36864);    // WB_state
        aF  = MFMA(ax, bF,  aF,  0, 0, 0);
        aG  = MFMA(ax, bG,  aG,  0, 0, 0);
        aFu = MFMA(au, bFu, aFu, 0, 0, 0);
        aSc = MFMA(au, bSc, aSc, 0, 0, 0);
    }
    const int e = w * 16 + l15;
    const float bxv = bx[e], buv = bu[e], bbv = bvec[e];
    #pragma unroll
    for (int r = 0; r < 4; ++r) {
        const int n = n0 + quad * 4 + r;
        const size_t o = (size_t)n * HD + e;
        float fuv = fmaxf(aFu[r] + buv, 0.f);
        float scv = tanhf(aSc[r]);
        float f = fmaxf(aF[r] + bxv, 0.f) + fuv;
        float xv = x0[o];
        float dx = -(bbv + f) * xv - aG[r] + f * scv;
        float xnv = fminf(fmaxf(xv + DT_C * dx, -1.f), 1.f);
        fu[o] = fuv; sc[o] = scv; xn[o] = xnv;
        xtT[((size_t)(n >> 5) * 64 + e) * 32 + (n & 31)] = f2bf(xnv);
    }
}

// ---------------- the mega-kernel ----------------
__global__ __launch_bounds__(256, 1) void lgtcn_kernel(
    const float* x0, const float* u, const float* S,
    const float* WAh, const float* WBh, const float* WAs, const float* WBs,
    const float* bx, const float* bu, const float* bvec,
    u16* SbT, u16* utT, u16* xtT, u16* WtT,
    float* Yp, float* fu, float* sc, float* xA, float* xB, float* out,
    int KS)
{
    cg::grid_group grid = cg::this_grid();

    prep_phase(S, u, x0, WAh, WAs, WBh, WBs, SbT, utT, xtT, WtT);
    grid.sync();

    diffuseA_phase(SbT, utT, xtT, Yp, KS);
    grid.sync();
    update1_phase(Yp, KS, WtT, bx, bu, bvec, x0, fu, sc, xA, xtT);
    grid.sync();

    diffuse_step_phase(SbT, xtT, Yp, KS);
    grid.sync();
    update_step_phase(Yp, KS, WtT, bx, bvec, fu, sc, xA, xB, xtT);
    grid.sync();

    diffuse_step_phase(SbT, xtT, Yp, KS);
    grid.sync();
    update_step_phase(Yp, KS, WtT, bx, bvec, fu, sc, xB, xA, xtT);
    grid.sync();

    diffuse_step_phase(SbT, xtT, Yp, KS);
    grid.sync();
    update_step_phase(Yp, KS, WtT, bx, bvec, fu, sc, xA, out, xtT);
}

extern "C" void kernel_launch(void* const* d_in, const int* in_sizes, int n_in,
                              void* d_out, int out_size, void* d_ws, size_t ws_size,
                              hipStream_t stream) {
    float* x   = (float*)d_in[0];
    float* u   = (float*)d_in[1];
    float* S   = (float*)d_in[2];
    float* WAh = (float*)d_in[3];
    float* WBh = (float*)d_in[4];
    float* WAs = (float*)d_in[5];
    float* WBs = (float*)d_in[6];
    float* bx  = (float*)d_in[7];
    float* bu  = (float*)d_in[8];
    float* bvec= (float*)d_in[9];
    float* out = (float*)d_out;

    const size_t sbf = (size_t)3 * NN * NN * 2;              // 100.7 MB
    const size_t small = 2 * 524288 + 98304 + 4 * (size_t)NN * HD * 4;
    int KS = 8;
    while (KS > 1 && ws_size < sbf + (size_t)KS * 6 * NN * HD * 4 + small) KS >>= 1;

    char* p = (char*)d_ws;
    u16* SbT  = (u16*)p;   p += sbf;
    float* Yp = (float*)p; p += (size_t)KS * 6 * NN * HD * 4;
    u16* utT  = (u16*)p;   p += 524288;
    u16* xtT  = (u16*)p;   p += 524288;
    u16* WtT  = (u16*)p;   p += 98304;
    float* fu = (float*)p; p += (size_t)NN * HD * 4;
    float* sc = (float*)p; p += (size_t)NN * HD * 4;
    float* xA = (float*)p; p += (size_t)NN * HD * 4;
    float* xB = (float*)p; p += (size_t)NN * HD * 4;

    void* args[] = {
        &x, &u, &S, &WAh, &WBh, &WAs, &WBs, &bx, &bu, &bvec,
        &SbT, &utT, &xtT, &WtT, &Yp, &fu, &sc, &xA, &xB, &out, &KS
    };
    hipLaunchCooperativeKernel((const void*)lgtcn_kernel,
                               dim3(256), dim3(256), args, 0, stream);
}